// Round 8
// baseline (295.630 us; speedup 1.0000x reference)
//
#include <hip/hip_runtime.h>
#include <hip/hip_bf16.h>

#define B_  8
#define S_  2048
#define H_  6
#define DK_ 24
#define DM_ 144

// tanh(SCALE*c) ~= c*(K0 + K1*t + K2*t^2), t = c^2, SCALE = 0.1/sqrt(24).
#define TK0  2.0412414523193153e-02f
#define TK1 -2.8350575726379381e-06f
#define TK2  4.7250959543965635e-10f

typedef __bf16 bf16x8 __attribute__((ext_vector_type(8)));
typedef __bf16 bf16x2 __attribute__((ext_vector_type(2)));
typedef float  f32x4  __attribute__((ext_vector_type(4)));

#define MFMA_ __builtin_amdgcn_mfma_f32_16x16x32_bf16

__device__ __forceinline__ unsigned short f2bf(float f) {
    return __builtin_bit_cast(unsigned short, (__bf16)f);
}
__device__ __forceinline__ uint pack2(float a, float b) {
    bf16x2 v; v[0] = (__bf16)a; v[1] = (__bf16)b;
    return __builtin_bit_cast(uint, v);
}
__device__ __forceinline__ float tanh_s(float c) {   // 4 VALU ops
    float t = c * c;
    float u = fmaf(t, TK2, TK1);
    u = fmaf(t, u, TK0);
    return c * u;
}

// ---------------------------------------------------------------------------
// prep_w: Whq[6][32][160] bf16 (head-sliced Wq, bias at k=144, zero pad) and
//         Wlp[144][160] bf16 (lin_w, bias at k=144).
// ---------------------------------------------------------------------------
__global__ __launch_bounds__(256)
void prep_w_kernel(const float* __restrict__ Wq, const float* __restrict__ Wqb,
                   const float* __restrict__ Wl, const float* __restrict__ lb,
                   ushort* __restrict__ Whq, ushort* __restrict__ Wlp) {
    int i = blockIdx.x * 256 + threadIdx.x;
    if (i < 30720) {                      // Whq: 6*32*160
        int h = i / 5120, rem = i % 5120;
        int d = rem / 160, c = rem % 160;
        float v = 0.f;
        if (d < DK_) {
            if (c < DM_)       v = Wq[(h * DK_ + d) * DM_ + c];
            else if (c == DM_) v = Wqb[h * DK_ + d];
        }
        Whq[i] = f2bf(v);
    } else if (i < 53760) {               // Wlp: 144*160
        int j = i - 30720;
        int r = j / 160, c = j % 160;
        float v = (c < DM_) ? Wl[r * DM_ + c] : (c == DM_ ? lb[r] : 0.f);
        Wlp[j] = f2bf(v);
    }
}

// ---------------------------------------------------------------------------
// prep_kv: K f32 -> Ktt[bh][kt][64 s][32 dk] bf16 (cols 24..31 zero), and
//          V f32 -> Vtt[bh][kt][32 d][64 s] bf16 (rows 24..31 zero).
// ---------------------------------------------------------------------------
__global__ __launch_bounds__(256)
void prep_kv_kernel(const float* __restrict__ K, const float* __restrict__ V,
                    ushort* __restrict__ Ktt, ushort* __restrict__ Vtt) {
    __shared__ float sv[64 * 25];
    const int t = threadIdx.x;
    const int kt = blockIdx.x, h = blockIdx.y, b = blockIdx.z;
    const int bh = b * H_ + h;
    const size_t tile = (size_t)(bh * 32 + kt);
    const float4* Ks = (const float4*)(K + ((size_t)bh * S_ + kt * 64) * DK_);
    ushort* Ko = Ktt + tile * 2048;
    for (int idx = t; idx < 384; idx += 256) {
        int r = idx / 6, c4 = (idx % 6) * 4;
        float4 v = Ks[idx];
        ushort4 u; u.x = f2bf(v.x); u.y = f2bf(v.y); u.z = f2bf(v.z); u.w = f2bf(v.w);
        *(ushort4*)&Ko[r * 32 + c4] = u;
    }
    if (t < 64) { uint4 z = {0u,0u,0u,0u}; *(uint4*)&Ko[t * 32 + 24] = z; }
    const float4* Vs = (const float4*)(V + ((size_t)bh * S_ + kt * 64) * DK_);
    for (int idx = t; idx < 384; idx += 256) {
        int r = idx / 6, c4 = (idx % 6) * 4;
        *(float4*)&sv[r * 25 + c4] = Vs[idx];
    }
    __syncthreads();
    int d = t >> 3, s8 = (t & 7) * 8;
    uint4 o = {0u,0u,0u,0u};
    if (d < DK_) {
        o.x = pack2(sv[(s8 + 0) * 25 + d], sv[(s8 + 1) * 25 + d]);
        o.y = pack2(sv[(s8 + 2) * 25 + d], sv[(s8 + 3) * 25 + d]);
        o.z = pack2(sv[(s8 + 4) * 25 + d], sv[(s8 + 5) * 25 + d]);
        o.w = pack2(sv[(s8 + 6) * 25 + d], sv[(s8 + 7) * 25 + d]);
    }
    ((uint4*)Vtt)[tile * 256 + t] = o;
}

// ---------------------------------------------------------------------------
// attn: fused qproj + tanh-attention, SPLIT-K across waves, barrier-free loop.
// Block = 256 threads (4 waves) = 64 q-rows of one (b,h).  Wave w owns
// k-tiles 4i+w (8 tiles): K/V frags loaded global->regs (pre-tiled layout IS
// the frag layout, coalesced, L2-resident); S^T strips -> tanh -> private
// 64x64 P in LDS -> PV into private accs.  Cross-wave reduce via ds_add_f32.
// ---------------------------------------------------------------------------
__global__ __launch_bounds__(256, 3)
void attn_kernel(const float* __restrict__ Q, const ushort* __restrict__ Whq,
                 const ushort* __restrict__ Ktt, const ushort* __restrict__ Vtt,
                 float* __restrict__ out) {
    __shared__ __attribute__((aligned(16))) char smem[51200];
    ushort* s_q  = (ushort*)smem;               // 64 x pitch40     [0, 5120)
    float*  s_ctx = (float*)(smem + 5120);      // 64 x pitch36 f32 [5120,14336)
    // per-wave P: smem + 14336 + w*9216, 64 x pitch72 ushort

    const int t = threadIdx.x;
    const int w = t >> 6, n16 = t & 15, g = (t >> 4) & 3;
    const int qp = blockIdx.x, h = blockIdx.y, b = blockIdx.z;
    const int bh = b * H_ + h;
    const int row0 = qp * 64;

    const uint4* Kb4 = (const uint4*)Ktt + (size_t)bh * 8192;   // 32 tiles x 256
    const uint4* Vb4 = (const uint4*)Vtt + (size_t)bh * 8192;
    const int koff = n16 * 4 + g;
    const int voff = n16 * 8 + g;
    const f32x4 zf = {0.f, 0.f, 0.f, 0.f};

    // early prefetch: K frags of first owned tile (kt = w), hidden by phase A
    bf16x8 kf[4];
#pragma unroll
    for (int mt = 0; mt < 4; ++mt)
        kf[mt] = __builtin_bit_cast(bf16x8, Kb4[w * 256 + mt * 64 + koff]);

    // ---- Phase A: q = Q @ Whq^T + bias (k=144 col); 4 waves x 16 rows ----
    const uint4* Wh4 = (const uint4*)Whq + h * 640;
    {
        const float* Qr = Q + (size_t)(b * S_ + row0 + w * 16 + n16) * DM_;
        f32x4 qa0 = zf, qa1 = zf;
#pragma unroll
        for (int ks = 0; ks < 5; ++ks) {
            bf16x8 av;
            if (ks < 4 || g < 2) {            // real cols (ks=4,g<2 -> 128..143)
                float4 f0 = *(const float4*)&Qr[ks * 32 + g * 8];
                float4 f1 = *(const float4*)&Qr[ks * 32 + g * 8 + 4];
                uint4 u;
                u.x = pack2(f0.x, f0.y); u.y = pack2(f0.z, f0.w);
                u.z = pack2(f1.x, f1.y); u.w = pack2(f1.z, f1.w);
                av = __builtin_bit_cast(bf16x8, u);
            } else {                          // k=144 bias col (g==2), zeros (g==3)
                uint4 u = {0u, 0u, 0u, 0u};
                if (g == 2) u.x = 0x00003F80u;
                av = __builtin_bit_cast(bf16x8, u);
            }
            bf16x8 bv0 = __builtin_bit_cast(bf16x8, Wh4[n16 * 20 + ks * 4 + g]);
            bf16x8 bv1 = __builtin_bit_cast(bf16x8, Wh4[(16 + n16) * 20 + ks * 4 + g]);
            qa0 = MFMA_(av, bv0, qa0, 0, 0, 0);
            qa1 = MFMA_(av, bv1, qa1, 0, 0, 0);
        }
#pragma unroll
        for (int reg = 0; reg < 4; ++reg) {   // transpose -> s_q[q][dk]
            int r = (w * 16 + g * 4 + reg) * 40;
            s_q[r + n16]      = f2bf(qa0[reg]);
            s_q[r + 16 + n16] = f2bf(qa1[reg]);   // d 24..31 zero via Whq rows
        }
    }
    for (int i = t; i < 2304; i += 256) s_ctx[i] = 0.f;   // zero reduce buffer
    __syncthreads();                                       // the ONLY pre-loop barrier

    bf16x8 qf[4];
#pragma unroll
    for (int j = 0; j < 4; ++j)
        qf[j] = *(const bf16x8*)&s_q[(j * 16 + n16) * 40 + g * 8];

    ushort* s_pw = (ushort*)(smem + 14336) + w * 4608;    // private 64 x 72
    f32x4 acc[4][2];
#pragma unroll
    for (int m = 0; m < 4; ++m) { acc[m][0] = zf; acc[m][1] = zf; }

    // ---- barrier-free k-loop: wave w handles tiles kt = 4i + w -----------
    for (int i = 0; i < 8; ++i) {
        const int kt = i * 4 + w;
        uint4 vl[4];                          // V frags: [dn*2+kc]
#pragma unroll
        for (int j = 0; j < 4; ++j)
            vl[j] = Vb4[kt * 256 + (j >> 1) * 128 + (j & 1) * 4 + voff];
        // S^T strips (all 64 q) + tanh -> P
#pragma unroll
        for (int mt = 0; mt < 4; ++mt) {
            f32x4 c0 = MFMA_(kf[mt], qf[0], zf, 0, 0, 0);
            f32x4 c1 = MFMA_(kf[mt], qf[1], zf, 0, 0, 0);
            f32x4 c2 = MFMA_(kf[mt], qf[2], zf, 0, 0, 0);
            f32x4 c3 = MFMA_(kf[mt], qf[3], zf, 0, 0, 0);
            uint2 u;
            u.x = pack2(tanh_s(c0[0]), tanh_s(c0[1]));
            u.y = pack2(tanh_s(c0[2]), tanh_s(c0[3]));
            *(uint2*)&s_pw[n16 * 72 + mt * 16 + g * 4] = u;
            u.x = pack2(tanh_s(c1[0]), tanh_s(c1[1]));
            u.y = pack2(tanh_s(c1[2]), tanh_s(c1[3]));
            *(uint2*)&s_pw[(16 + n16) * 72 + mt * 16 + g * 4] = u;
            u.x = pack2(tanh_s(c2[0]), tanh_s(c2[1]));
            u.y = pack2(tanh_s(c2[2]), tanh_s(c2[3]));
            *(uint2*)&s_pw[(32 + n16) * 72 + mt * 16 + g * 4] = u;
            u.x = pack2(tanh_s(c3[0]), tanh_s(c3[1]));
            u.y = pack2(tanh_s(c3[2]), tanh_s(c3[3]));
            *(uint2*)&s_pw[(48 + n16) * 72 + mt * 16 + g * 4] = u;
        }
        {   // prefetch next owned tile's K (kf dead after strips above)
            const int ktn = (kt + 4) & 31;
#pragma unroll
            for (int mt = 0; mt < 4; ++mt)
                kf[mt] = __builtin_bit_cast(bf16x8, Kb4[ktn * 256 + mt * 64 + koff]);
        }
        // PV: P (wave-private, in-order DS) x V frags
#pragma unroll
        for (int mt2 = 0; mt2 < 4; ++mt2) {
            bf16x8 ap0 = *(const bf16x8*)&s_pw[(mt2 * 16 + n16) * 72 + g * 8];
            bf16x8 ap1 = *(const bf16x8*)&s_pw[(mt2 * 16 + n16) * 72 + 32 + g * 8];
            acc[mt2][0] = MFMA_(ap0, __builtin_bit_cast(bf16x8, vl[0]), acc[mt2][0], 0, 0, 0);
            acc[mt2][0] = MFMA_(ap1, __builtin_bit_cast(bf16x8, vl[1]), acc[mt2][0], 0, 0, 0);
            acc[mt2][1] = MFMA_(ap0, __builtin_bit_cast(bf16x8, vl[2]), acc[mt2][1], 0, 0, 0);
            acc[mt2][1] = MFMA_(ap1, __builtin_bit_cast(bf16x8, vl[3]), acc[mt2][1], 0, 0, 0);
        }
    }

    // ---- cross-wave k-reduction: ds_add_f32 into s_ctx -------------------
#pragma unroll
    for (int mt2 = 0; mt2 < 4; ++mt2) {
#pragma unroll
        for (int reg = 0; reg < 4; ++reg) {
            int q = mt2 * 16 + g * 4 + reg;
            atomicAdd(&s_ctx[q * 36 + n16], acc[mt2][0][reg]);
            if (n16 < 8) atomicAdd(&s_ctx[q * 36 + 16 + n16], acc[mt2][1][reg]);
        }
    }
    __syncthreads();
    for (int idx = t; idx < 384; idx += 256) {
        int r = idx / 6, c = idx % 6;
        float4 v4 = *(const float4*)&s_ctx[r * 36 + c * 4];
        *(float4*)&out[((size_t)b * S_ + row0 + r) * DM_ + h * DK_ + c * 4] = v4;
    }
}

// ---------------------------------------------------------------------------
// outln: out = LN(ctx @ Wl^T + lb + residual) * g + beta, in-place on d_out.
// ---------------------------------------------------------------------------
__global__ __launch_bounds__(512)
void outln_kernel(const float* __restrict__ Qres, const ushort* __restrict__ Wlp,
                  const float* __restrict__ lg, const float* __restrict__ lbeta,
                  float* __restrict__ io) {
    __shared__ __attribute__((aligned(16))) ushort s_a[64 * 168];
    __shared__ __attribute__((aligned(16))) ushort s_w[144 * 168];
    __shared__ float s_red[2][2][64];
    const int t = threadIdx.x;
    const int w = t >> 6, n16 = t & 15, g = (t >> 4) & 3;
    const int wq = w & 3, half = w >> 2;
    const int nt_base = half * 5, nt_cnt = half ? 4 : 5;
    const int row0 = blockIdx.x * 64;

    for (int idx = t; idx < 2304; idx += 512) {
        int r = idx / 36, c4 = (idx % 36) * 4;
        float4 v = *(const float4*)&io[(size_t)(row0 + r) * DM_ + c4];
        uint2 u; u.x = pack2(v.x, v.y); u.y = pack2(v.z, v.w);
        *(uint2*)&s_a[r * 168 + c4] = u;
    }
    if (t < 64) {
        uint4 pad = {0x00003F80u, 0u, 0u, 0u};
        uint4 z4  = {0u, 0u, 0u, 0u};
        *(uint4*)&s_a[t * 168 + 144] = pad;
        *(uint4*)&s_a[t * 168 + 152] = z4;
    }
    for (int idx = t; idx < 2880; idx += 512) {
        int r = idx / 20, c8 = (idx % 20) * 8;
        *(uint4*)&s_w[r * 168 + c8] = *(const uint4*)&Wlp[r * 160 + c8];
    }
    __syncthreads();

    f32x4 acc[5];
#pragma unroll
    for (int j = 0; j < 5; ++j) acc[j] = (f32x4){0.f, 0.f, 0.f, 0.f};
#pragma unroll
    for (int ks = 0; ks < 5; ++ks) {
        bf16x8 av = *(const bf16x8*)&s_a[(wq * 16 + n16) * 168 + ks * 32 + g * 8];
        for (int j = 0; j < nt_cnt; ++j) {
            bf16x8 bv = *(const bf16x8*)&s_w[((nt_base + j) * 16 + n16) * 168 + ks * 32 + g * 8];
            acc[j] = MFMA_(av, bv, acc[j], 0, 0, 0);
        }
    }
    float vals[5][4], s1[4] = {0, 0, 0, 0}, s2[4] = {0, 0, 0, 0};
    for (int j = 0; j < nt_cnt; ++j) {
        int d = (nt_base + j) * 16 + n16;
#pragma unroll
        for (int reg = 0; reg < 4; ++reg) {
            int row = row0 + wq * 16 + g * 4 + reg;
            float v = acc[j][reg] + Qres[(size_t)row * DM_ + d];
            vals[j][reg] = v;
            s1[reg] += v; s2[reg] = fmaf(v, v, s2[reg]);
        }
    }
#pragma unroll
    for (int off = 1; off < 16; off <<= 1) {
#pragma unroll
        for (int reg = 0; reg < 4; ++reg) {
            s1[reg] += __shfl_xor(s1[reg], off);
            s2[reg] += __shfl_xor(s2[reg], off);
        }
    }
    if (n16 == 0) {
#pragma unroll
        for (int reg = 0; reg < 4; ++reg) {
            int rr = wq * 16 + g * 4 + reg;
            s_red[half][0][rr] = s1[reg];
            s_red[half][1][rr] = s2[reg];
        }
    }
    __syncthreads();
    float mu[4], rs[4];
#pragma unroll
    for (int reg = 0; reg < 4; ++reg) {
        int rr = wq * 16 + g * 4 + reg;
        float S1 = s_red[0][0][rr] + s_red[1][0][rr];
        float S2 = s_red[0][1][rr] + s_red[1][1][rr];
        float m = S1 * (1.f / 144.f);
        mu[reg] = m;
        rs[reg] = rsqrtf(S2 * (1.f / 144.f) - m * m + 1e-5f);
    }
    for (int j = 0; j < nt_cnt; ++j) {
        int d = (nt_base + j) * 16 + n16;
        float gv = lg[d], bv = lbeta[d];
#pragma unroll
        for (int reg = 0; reg < 4; ++reg) {
            int row = row0 + wq * 16 + g * 4 + reg;
            io[(size_t)row * DM_ + d] = (vals[j][reg] - mu[reg]) * rs[reg] * gv + bv;
        }
    }
}

// ---------------------------------------------------------------------------
extern "C" void kernel_launch(void* const* d_in, const int* in_sizes, int n_in,
                              void* d_out, int out_size, void* d_ws, size_t ws_size,
                              hipStream_t stream) {
    const float* Q     = (const float*)d_in[0];
    const float* K     = (const float*)d_in[1];
    const float* V     = (const float*)d_in[2];
    // d_in[3] = attn_mask: dead code in the reference, ignored.
    const float* Wq_w  = (const float*)d_in[4];
    const float* Wq_b  = (const float*)d_in[5];
    const float* lin_w = (const float*)d_in[6];
    const float* lin_b = (const float*)d_in[7];
    const float* ln_g  = (const float*)d_in[8];
    const float* ln_b  = (const float*)d_in[9];
    float* out = (float*)d_out;

    ushort* Ktt = (ushort*)d_ws;                            // 6,291,456 B
    ushort* Vtt = (ushort*)((char*)d_ws + 6291456);         // 6,291,456 B
    ushort* Whq = (ushort*)((char*)d_ws + 12582912);        // 61,440 B
    ushort* Wlp = (ushort*)((char*)d_ws + 12644352);        // 46,080 B

    prep_w_kernel<<<210, 256, 0, stream>>>(Wq_w, Wq_b, lin_w, lin_b, Whq, Wlp);
    prep_kv_kernel<<<dim3(32, H_, B_), 256, 0, stream>>>(K, V, Ktt, Vtt);
    attn_kernel<<<dim3(S_ / 64, H_, B_), 256, 0, stream>>>(Q, Whq, Ktt, Vtt, out);
    outln_kernel<<<(B_ * S_) / 64, 512, 0, stream>>>(Q, Wlp, ln_g, ln_b, out);
}